// Round 1
// baseline (3697.666 us; speedup 1.0000x reference)
//
#include <hip/hip_runtime.h>

#define N_NODES 100000
#define N_EDGES 1000000
#define DIM 64

static const long long ND = (long long)N_NODES * DIM;  // 6,400,000

// d_out layout (floats):
// h1: [0, ND)
// h2: [ND, 2*ND)
// c1: [2*ND, 2*ND+64)
// c2: [2*ND+64, 2*ND+128)
// h3: [2*ND+128, 3*ND+128)
// h4: [3*ND+128, 4*ND+128)

__global__ void k_zero(float* __restrict__ out, float* __restrict__ ws_c, long long n4) {
    long long i = (long long)blockIdx.x * blockDim.x + threadIdx.x;
    long long stride = (long long)gridDim.x * blockDim.x;
    float4* o4 = (float4*)out;
    float4 z = make_float4(0.f, 0.f, 0.f, 0.f);
    for (long long j = i; j < n4; j += stride) o4[j] = z;
    if (blockIdx.x == 0 && threadIdx.x < 128) ws_c[threadIdx.x] = 0.f;
}

// One graph's edges; scatter feat -> out_a, shuf -> out_b. 16 lanes per edge, float4 each.
__global__ __launch_bounds__(256) void k_scatter(const int* __restrict__ src,
                                                 const int* __restrict__ dst,
                                                 const float* __restrict__ feat,
                                                 const float* __restrict__ shuf,
                                                 float* __restrict__ out_a,
                                                 float* __restrict__ out_b) {
    long long tid = (long long)blockIdx.x * blockDim.x + threadIdx.x;
    int e = (int)(tid >> 4);
    int c = (int)(tid & 15) * 4;
    if (e >= N_EDGES) return;
    int s = src[e];
    int d = dst[e];
    const float4 f = *(const float4*)(feat + (long long)s * DIM + c);
    const float4 g = *(const float4*)(shuf + (long long)s * DIM + c);
    float* pa = out_a + (long long)d * DIM + c;
    float* pb = out_b + (long long)d * DIM + c;
    unsafeAtomicAdd(pa + 0, f.x);
    unsafeAtomicAdd(pa + 1, f.y);
    unsafeAtomicAdd(pa + 2, f.z);
    unsafeAtomicAdd(pa + 3, f.w);
    unsafeAtomicAdd(pb + 0, g.x);
    unsafeAtomicAdd(pb + 1, g.y);
    unsafeAtomicAdd(pb + 2, g.z);
    unsafeAtomicAdd(pb + 3, g.w);
}

// In-place per-row linear: h[r] = agg[r] @ W + b. One wave per row, 16 rows per wave.
// buf = blockIdx.y: 0->h1(W1) 1->h2(W2) 2->h3(W1) 3->h4(W2).
// For buf<2, accumulate column sums into ws_c[buf*64 + lane].
__global__ __launch_bounds__(256) void k_transform(float* __restrict__ out,
                                                   const float* __restrict__ W1,
                                                   const float* __restrict__ b1,
                                                   const float* __restrict__ W2,
                                                   const float* __restrict__ b2,
                                                   float* __restrict__ ws_c) {
    const int buf = blockIdx.y;
    const long long hoff[4] = {0, ND, 2 * ND + 128, 3 * ND + 128};
    const float* W = (buf & 1) ? W2 : W1;
    const float* bias = (buf & 1) ? b2 : b1;

    __shared__ float Wl[64 * 64];
    __shared__ float csum_l[4][64];

    int t = threadIdx.x;
    for (int i = t; i < 64 * 64; i += 256) Wl[i] = W[i];
    __syncthreads();

    int wave = t >> 6;
    int lane = t & 63;
    float bj = bias[lane];
    float* base = out + hoff[buf];

    float csum = 0.f;
    int row0 = blockIdx.x * 64 + wave * 16;
    int rend = row0 + 16;
    if (rend > N_NODES) rend = N_NODES;
    for (int r = row0; r < rend; ++r) {
        float a = base[(long long)r * DIM + lane];
        float acc = bj;
        #pragma unroll
        for (int k = 0; k < 64; ++k) {
            acc += __shfl(a, k) * Wl[k * 64 + lane];
        }
        base[(long long)r * DIM + lane] = acc;
        csum += acc;
    }

    if (buf < 2) {
        csum_l[wave][lane] = csum;
        __syncthreads();
        if (wave == 0) {
            float s = csum_l[0][lane] + csum_l[1][lane] + csum_l[2][lane] + csum_l[3][lane];
            unsafeAtomicAdd(&ws_c[buf * 64 + lane], s);
        }
    }
}

__global__ void k_final(const float* __restrict__ ws_c, float* __restrict__ out_c) {
    int t = threadIdx.x;  // 128 threads: 0..63 -> c1, 64..127 -> c2
    float m = ws_c[t] * (1.0f / (float)N_NODES);
    out_c[t] = 1.f / (1.f + expf(-m));
}

extern "C" void kernel_launch(void* const* d_in, const int* in_sizes, int n_in,
                              void* d_out, int out_size, void* d_ws, size_t ws_size,
                              hipStream_t stream) {
    const float* feat = (const float*)d_in[0];
    const float* shuf = (const float*)d_in[1];
    const int* src1 = (const int*)d_in[2];
    const int* dst1 = (const int*)d_in[3];
    const int* src2 = (const int*)d_in[4];
    const int* dst2 = (const int*)d_in[5];
    const float* W1 = (const float*)d_in[6];
    const float* b1 = (const float*)d_in[7];
    const float* W2 = (const float*)d_in[8];
    const float* b2 = (const float*)d_in[9];

    float* out = (float*)d_out;
    float* ws_c = (float*)d_ws;

    float* h1 = out;
    float* h2 = out + ND;
    float* c_out = out + 2 * ND;            // 128 floats (c1 then c2)
    float* h3 = out + 2 * ND + 128;
    float* h4 = out + 3 * ND + 128;

    // 1) zero outputs + c accumulators
    long long n4 = (4 * ND + 128) / 4;
    k_zero<<<4096, 256, 0, stream>>>(out, ws_c, n4);

    // 2) scatter-add per graph (feat and shuf fused)
    int scatter_blocks = (N_EDGES * 16 + 255) / 256;
    k_scatter<<<scatter_blocks, 256, 0, stream>>>(src1, dst1, feat, shuf, h1, h3);
    k_scatter<<<scatter_blocks, 256, 0, stream>>>(src2, dst2, feat, shuf, h2, h4);

    // 3) in-place linear + column sums of h1/h2
    dim3 tgrid((N_NODES + 63) / 64, 4);
    k_transform<<<tgrid, 256, 0, stream>>>(out, W1, b1, W2, b2, ws_c);

    // 4) c = sigmoid(mean)
    k_final<<<1, 128, 0, stream>>>(ws_c, c_out);
}

// Round 2
// 836.012 us; speedup vs baseline: 4.4230x; 4.4230x over previous
//
#include <hip/hip_runtime.h>

#define N_NODES 100000
#define N_EDGES 1000000
#define DIM 64

static const long long ND = (long long)N_NODES * DIM;  // 6,400,000

// d_out layout (floats):
// h1: [0, ND)  h2: [ND, 2*ND)  c1c2: [2*ND, 2*ND+128)  h3: [2*ND+128, ...)  h4: [3*ND+128, ...)

// d_ws layout (4-byte units):
// cursor1 [0, 100000)            -- doubles as histogram for graph1
// cursor2 [100000, 200000)       -- histogram for graph2
// off1    [200000, 300001)
// off2    [300001, 400002)
// sorted1 [400002, 1400002)      -- src node ids, grouped by dst
// sorted2 [1400002, 2400002)
// csum    [2400002, 2400130)     -- float column sums: [0,64)=h1, [64,128)=h2
#define WS_CURSOR1 0
#define WS_CURSOR2 100000
#define WS_OFF1    200000
#define WS_OFF2    300001
#define WS_SORTED1 400002
#define WS_SORTED2 1400002
#define WS_CSUM    2400002

__global__ void k_init(int* __restrict__ ws) {
    int i = blockIdx.x * blockDim.x + threadIdx.x;
    if (i < 200000) ws[i] = 0;                       // cursor1+cursor2 (= histograms)
    else if (i < 200128) ((float*)ws)[WS_CSUM + (i - 200000)] = 0.f;
}

__global__ __launch_bounds__(256) void k_hist(const int* __restrict__ dst1,
                                              const int* __restrict__ dst2,
                                              int* __restrict__ ws) {
    int i = blockIdx.x * blockDim.x + threadIdx.x;
    if (i < N_EDGES) atomicAdd(&ws[WS_CURSOR1 + dst1[i]], 1);
    else if (i < 2 * N_EDGES) atomicAdd(&ws[WS_CURSOR2 + dst2[i - N_EDGES]], 1);
}

// One block per graph (blockIdx.y). 1024 threads, each scans a contiguous chunk.
// Reads histogram from cursor area, writes exclusive prefix to off AND back to cursor.
__global__ __launch_bounds__(1024) void k_scan(int* __restrict__ ws) {
    const int g = blockIdx.y;
    int* hist = ws + (g ? WS_CURSOR2 : WS_CURSOR1);
    int* off  = ws + (g ? WS_OFF2 : WS_OFF1);

    __shared__ int s[1024];
    const int t = threadIdx.x;
    const int CH = 98;                               // 1024*98 >= 100000
    int start = t * CH;
    int end = start + CH; if (end > N_NODES) end = N_NODES;

    int local = 0;
    for (int i = start; i < end; ++i) local += hist[i];
    s[t] = local;
    __syncthreads();
    for (int d = 1; d < 1024; d <<= 1) {
        int v = 0;
        if (t >= d) v = s[t - d];
        __syncthreads();
        if (t >= d) s[t] += v;
        __syncthreads();
    }
    int run = (t == 0) ? 0 : s[t - 1];
    for (int i = start; i < end; ++i) {
        int h = hist[i];
        off[i] = run;
        hist[i] = run;                               // cursor = start position
        run += h;
    }
    if (t == 1023) off[N_NODES] = s[1023];
}

__global__ __launch_bounds__(256) void k_fill(const int* __restrict__ src1,
                                              const int* __restrict__ dst1,
                                              const int* __restrict__ src2,
                                              const int* __restrict__ dst2,
                                              int* __restrict__ ws) {
    int i = blockIdx.x * blockDim.x + threadIdx.x;
    if (i < N_EDGES) {
        int pos = atomicAdd(&ws[WS_CURSOR1 + dst1[i]], 1);
        ws[WS_SORTED1 + pos] = src1[i];
    } else if (i < 2 * N_EDGES) {
        int e = i - N_EDGES;
        int pos = atomicAdd(&ws[WS_CURSOR2 + dst2[e]], 1);
        ws[WS_SORTED2 + pos] = src2[e];
    }
}

// blockIdx.y = graph. 4 waves/block, 8 nodes per wave. Wave lane = output dim.
// Aggregates feat & shuf rows over the node's incident edges, applies W (LDS),
// writes h rows, accumulates column sums for the feat branch.
__global__ __launch_bounds__(256) void k_gather(const int* __restrict__ ws,
                                                const float* __restrict__ feat,
                                                const float* __restrict__ shuf,
                                                const float* __restrict__ W1,
                                                const float* __restrict__ b1,
                                                const float* __restrict__ W2,
                                                const float* __restrict__ b2,
                                                float* __restrict__ out) {
    const int g = blockIdx.y;
    const int* off    = ws + (g ? WS_OFF2 : WS_OFF1);
    const int* sorted = ws + (g ? WS_SORTED2 : WS_SORTED1);
    const float* W    = g ? W2 : W1;
    const float* bias = g ? b2 : b1;
    float* h_f = out + (g ? ND : 0);                  // h2 : h1
    float* h_s = out + (g ? 3 * ND + 128 : 2 * ND + 128);  // h4 : h3
    float* csum = (float*)ws + WS_CSUM + g * 64;

    __shared__ float Wl[64 * 64];
    __shared__ float red[4][64];

    const int t = threadIdx.x;
    for (int i = t; i < 64 * 64; i += 256) Wl[i] = W[i];
    __syncthreads();

    const int wave = t >> 6;
    const int lane = t & 63;
    const float bj = bias[lane];

    float csum_acc = 0.f;
    const int nb = blockIdx.x * 32 + wave * 8;
    for (int r = 0; r < 8; ++r) {
        const int n = nb + r;
        if (n >= N_NODES) break;
        const int e0 = off[n];
        const int e1 = off[n + 1];
        float accf = 0.f, accs = 0.f;
        for (int e = e0; e < e1; ++e) {
            const int s = sorted[e];
            accf += feat[(long long)s * DIM + lane];
            accs += shuf[(long long)s * DIM + lane];
        }
        float hf = bj, hs = bj;
        #pragma unroll
        for (int k = 0; k < 64; ++k) {
            const float wk = Wl[k * 64 + lane];
            hf += __shfl(accf, k) * wk;
            hs += __shfl(accs, k) * wk;
        }
        h_f[(long long)n * DIM + lane] = hf;
        h_s[(long long)n * DIM + lane] = hs;
        csum_acc += hf;
    }

    red[wave][lane] = csum_acc;
    __syncthreads();
    if (wave == 0) {
        float s = red[0][lane] + red[1][lane] + red[2][lane] + red[3][lane];
        unsafeAtomicAdd(&csum[lane], s);
    }
}

__global__ void k_final(const float* __restrict__ ws_csum, float* __restrict__ out_c) {
    int t = threadIdx.x;  // 128 threads: 0..63 -> c1, 64..127 -> c2
    float m = ws_csum[t] * (1.0f / (float)N_NODES);
    out_c[t] = 1.f / (1.f + expf(-m));
}

extern "C" void kernel_launch(void* const* d_in, const int* in_sizes, int n_in,
                              void* d_out, int out_size, void* d_ws, size_t ws_size,
                              hipStream_t stream) {
    const float* feat = (const float*)d_in[0];
    const float* shuf = (const float*)d_in[1];
    const int* src1 = (const int*)d_in[2];
    const int* dst1 = (const int*)d_in[3];
    const int* src2 = (const int*)d_in[4];
    const int* dst2 = (const int*)d_in[5];
    const float* W1 = (const float*)d_in[6];
    const float* b1 = (const float*)d_in[7];
    const float* W2 = (const float*)d_in[8];
    const float* b2 = (const float*)d_in[9];

    float* out = (float*)d_out;
    int* ws = (int*)d_ws;
    float* c_out = out + 2 * ND;

    k_init<<<(200128 + 255) / 256, 256, 0, stream>>>(ws);
    k_hist<<<(2 * N_EDGES + 255) / 256, 256, 0, stream>>>(dst1, dst2, ws);
    k_scan<<<dim3(1, 2), 1024, 0, stream>>>(ws);
    k_fill<<<(2 * N_EDGES + 255) / 256, 256, 0, stream>>>(src1, dst1, src2, dst2, ws);
    k_gather<<<dim3((N_NODES + 31) / 32, 2), 256, 0, stream>>>(
        ws, feat, shuf, W1, b1, W2, b2, out);
    k_final<<<1, 128, 0, stream>>>((const float*)ws + WS_CSUM, c_out);
}